// Round 3
// baseline (101.084 us; speedup 1.0000x reference)
//
#include <hip/hip_runtime.h>

#define DEVINL __device__ __forceinline__

typedef float f32x2 __attribute__((ext_vector_type(2)));

// ---------------------------------------------------------------------------
// Compile-time circuit constants via GF(2) linear-map tracking.
// Physical index p (10 bits): bits 9..4 = lane (6 bits), bits 3..0 = reg (4).
// Logical amplitude index a = A * p (A over GF(2)).  CNOT(c,t) => A row update
// with NO data movement.  A 1q gate on wire w pairs p with p ^ (A^{-1} e_{9-w});
// side bit = parity(row_{9-w}(A) & p).
//
// Round-3 (LDS-pipe-bound: VALUBusy 58%, ~330 LDS ops/wave on one shared port):
//  * Pipe rebalance: xor1/3 gates -> DPP quad_perm (VALU); xor48 gates (w0,w9)
//    -> v_permlane32_swap + v_permlane16_swap (VALU) with convention-
//    independent partner recovery b = (res0+res1) - v.  Only xor24/12/6
//    gates (w1,w2,w3) remain on ds_swizzle.
//  * Constants moved out of LDS: 1-block prep kernel -> __device__ g_cst[];
//    main kernel reads via uniform scalar loads. No __shared__, no barrier.
//  * Reduce: DPP quad-reduce all 10, pack to 3 values by quad-slot, then
//    xor4/8 swizzle + xor16/32 permlane-sum (exact).  60 LDS -> 6 LDS.
//  * Amplitudes as packed {re,im} f32x2 -> v_pk_fma_f32 gate updates.
//  * Gates commute (distinct logical wires): interleave LDS-gates with
//    VALU-gates so both pipes stay fed within a wave.
// ---------------------------------------------------------------------------
struct GC { int laneXor, regXor, rowL, rowR; };
struct Circ { GC g[20]; int sgnL[10], sgnR[10]; };

constexpr Circ build_circ() {
    Circ c{};
    unsigned A[10] = {};
    for (int i = 0; i < 10; ++i) A[i] = 1u << i;
    for (int w = 0; w < 10; ++w) {
        int pos = 9 - w;
        unsigned m = 1u << pos;
        c.g[w] = GC{ int(m >> 4), int(m & 15u), int(m >> 4), int(m & 15u) };
    }
    // layer 0 CNOT ring, range r=1
    for (int q = 0; q < 10; ++q) { int pc = 9 - q, pt = 9 - ((q + 1) % 10); A[pt] ^= A[pc]; }
    // invert A over GF(2)
    unsigned M[10] = {}, Inv[10] = {};
    for (int i = 0; i < 10; ++i) { M[i] = A[i]; Inv[i] = 1u << i; }
    for (int col = 0; col < 10; ++col) {
        int piv = col;
        while (!((M[piv] >> col) & 1u)) ++piv;
        unsigned tm = M[col]; M[col] = M[piv]; M[piv] = tm;
        unsigned ti = Inv[col]; Inv[col] = Inv[piv]; Inv[piv] = ti;
        for (int r = 0; r < 10; ++r)
            if (r != col && ((M[r] >> col) & 1u)) { M[r] ^= M[col]; Inv[r] ^= Inv[col]; }
    }
    // layer 1 Rot gates: m = A^{-1} e_pos, row = A[pos]
    for (int w = 0; w < 10; ++w) {
        int pos = 9 - w;
        unsigned m = 0;
        for (int i = 0; i < 10; ++i) m |= ((Inv[i] >> pos) & 1u) << i;
        unsigned row = A[pos];
        c.g[10 + w] = GC{ int(m >> 4), int(m & 15u), int(row >> 4), int(row & 15u) };
    }
    // layer 1 CNOT ring, range r=2
    for (int q = 0; q < 10; ++q) { int pc = 9 - q, pt = 9 - ((q + 2) % 10); A[pt] ^= A[pc]; }
    for (int q = 0; q < 10; ++q) { unsigned row = A[9 - q]; c.sgnL[q] = int(row >> 4); c.sgnR[q] = int(row & 15u); }
    return c;
}

constexpr Circ CC = build_circ();

// Phase-folding below relies on exactly these rows.
static_assert(CC.g[10].rowL == 31 && CC.g[10].rowR == 15, "w0 row");
static_assert(CC.g[11].rowL == 48 && CC.g[11].rowR == 0,  "w1 row");
static_assert(CC.g[12].rowL == 56 && CC.g[12].rowR == 0,  "w2 row");
static_assert(CC.g[13].rowL == 60 && CC.g[13].rowR == 0,  "w3 row");
static_assert(CC.g[14].rowL == 62 && CC.g[14].rowR == 0,  "w4 row");
static_assert(CC.g[15].rowL == 63 && CC.g[15].rowR == 0,  "w5 row");
static_assert(CC.g[16].rowL == 63 && CC.g[16].rowR == 8,  "w6 row");
static_assert(CC.g[17].rowL == 63 && CC.g[17].rowR == 12, "w7 row");
static_assert(CC.g[18].rowL == 63 && CC.g[18].rowR == 14, "w8 row");
static_assert(CC.g[19].rowL == 63 && CC.g[19].rowR == 15, "w9 row");
// Gate laneXor inventory this schedule depends on (derived: A rows are
// suffix-masks after the r=1 ring, so m = e_{pos-1}^e_pos except the ends).
static_assert(CC.g[10].laneXor == 48 && CC.g[10].regXor == 0, "w0 m");
static_assert(CC.g[11].laneXor == 24 && CC.g[12].laneXor == 12, "w1/w2 m");
static_assert(CC.g[13].laneXor == 6  && CC.g[14].laneXor == 3,  "w3/w4 m");
static_assert(CC.g[15].laneXor == 1  && CC.g[15].regXor == 8,   "w5 m");
static_assert(CC.g[16].laneXor == 0 && CC.g[16].regXor == 12, "w6 m");
static_assert(CC.g[17].laneXor == 0 && CC.g[17].regXor == 6,  "w7 m");
static_assert(CC.g[18].laneXor == 0 && CC.g[18].regXor == 3,  "w8 m");
static_assert(CC.g[19].laneXor == 48 && CC.g[19].regXor == 1,   "w9 m");

#if __has_builtin(__builtin_amdgcn_permlane32_swap)
#define HAS_PL32 1
#else
#define HAS_PL32 0
#endif
#if __has_builtin(__builtin_amdgcn_permlane16_swap)
#define HAS_PL16 1
#else
#define HAS_PL16 0
#endif

// sign-word xor: sw has the sign in bit 31 (or is 0)
DEVINL float csw(float v, int sw) {
    return __int_as_float(__float_as_int(v) ^ sw);
}

// partner value across lane^32 / lane^48, convention-independent:
// same-reg permlaneN_swap returns the two half-duplicated patterns; their sum
// is the pair-sum, so partner = sum - self (FP error ~1 ulp, tol is 4e-3).
DEVINL float xor32_val(float v, int lane) {
#if HAS_PL32
    auto r = __builtin_amdgcn_permlane32_swap(__float_as_int(v), __float_as_int(v), false, false);
    return (__int_as_float(r[0]) + __int_as_float(r[1])) - v;
#else
    return __int_as_float(__builtin_amdgcn_ds_bpermute((lane ^ 32) << 2, __float_as_int(v)));
#endif
}
DEVINL float xor48_val(float v, int lane) {
#if HAS_PL32 && HAS_PL16
    float t = xor32_val(v, lane);
    auto r = __builtin_amdgcn_permlane16_swap(__float_as_int(t), __float_as_int(t), false, false);
    return (__int_as_float(r[0]) + __int_as_float(r[1])) - t;
#else
    return __int_as_float(__builtin_amdgcn_ds_bpermute((lane ^ 48) << 2, __float_as_int(v)));
#endif
}
// butterfly sums (v + v[lane^N]) for the reduction — exact, convention-indep
DEVINL float bsum16(float v, int lane) {
#if HAS_PL16
    auto r = __builtin_amdgcn_permlane16_swap(__float_as_int(v), __float_as_int(v), false, false);
    return __int_as_float(r[0]) + __int_as_float(r[1]);
#else
    return v + __int_as_float(__builtin_amdgcn_ds_swizzle(__float_as_int(v), 0x1F | (16 << 10)));
#endif
}
DEVINL float bsum32(float v, int lane) {
#if HAS_PL32
    auto r = __builtin_amdgcn_permlane32_swap(__float_as_int(v), __float_as_int(v), false, false);
    return __int_as_float(r[0]) + __int_as_float(r[1]);
#else
    return v + __int_as_float(__builtin_amdgcn_ds_bpermute((lane ^ 32) << 2, __float_as_int(v)));
#endif
}

// lane-xor fetch: DPP (VALU) for 1..3, permlane (VALU) for 32/48, else swizzle
template<int XOR>
DEVINL float fetch(float v, int lane) {
    if constexpr (XOR == 0)      return v;
    else if constexpr (XOR == 1) return __int_as_float(__builtin_amdgcn_update_dpp(0, __float_as_int(v), 0xB1, 0xF, 0xF, true));
    else if constexpr (XOR == 2) return __int_as_float(__builtin_amdgcn_update_dpp(0, __float_as_int(v), 0x4E, 0xF, 0xF, true));
    else if constexpr (XOR == 3) return __int_as_float(__builtin_amdgcn_update_dpp(0, __float_as_int(v), 0x1B, 0xF, 0xF, true));
    else if constexpr (XOR == 32) return xor32_val(v, lane);
    else if constexpr (XOR == 48) return xor48_val(v, lane);
    else if constexpr (XOR < 32) return __int_as_float(__builtin_amdgcn_ds_swizzle(__float_as_int(v), 0x1F | (XOR << 10)));
    else return __int_as_float(__builtin_amdgcn_ds_bpermute((lane ^ XOR) << 2, __float_as_int(v)));
}

// ---------------------------------------------------------------------------
// Constants, computed once by qprep:
// [0..39]  layer-0 Rot mats (u00r,u00i,u01r,u01i per wire)
// [40..49] layer-1 tan(th/2) per wire
// [50..69] layer-1 (cos(phi/2), -sin(phi/2)) per wire
// [70]     prod_w cos(th_w/2)
// ---------------------------------------------------------------------------
__device__ __attribute__((aligned(16))) float g_cst[80];

__global__ void qprep(const float* __restrict__ qw) {
    int g = threadIdx.x;
    if (g < 10) {
        float phi = qw[g * 3 + 0], th = qw[g * 3 + 1], om = qw[g * 3 + 2];
        float c = cosf(0.5f * th), s = sinf(0.5f * th);
        float apo = 0.5f * (phi + om), amo = 0.5f * (phi - om);
        g_cst[g * 4 + 0] =  cosf(apo) * c;
        g_cst[g * 4 + 1] = -sinf(apo) * c;
        g_cst[g * 4 + 2] = -cosf(amo) * s;
        g_cst[g * 4 + 3] = -sinf(amo) * s;
    } else if (g < 20) {
        int w = g - 10;
        float phi = qw[g * 3 + 0], th = qw[g * 3 + 1];
        float c = cosf(0.5f * th), s = sinf(0.5f * th);
        g_cst[40 + w] = s / c;
        g_cst[50 + w * 2 + 0] =  cosf(0.5f * phi);
        g_cst[50 + w * 2 + 1] = -sinf(0.5f * phi);
    } else if (g == 20) {
        float p = 1.f;
        for (int w = 0; w < 10; ++w) p *= cosf(0.5f * qw[(10 + w) * 3 + 1]);
        g_cst[70] = p;
    }
}

// per-wire embedding factor: |0> --RY(x)--> --Rot(layer0)--> (a0, a1)
DEVINL void wf(const float* cst, float xw, int w,
               float& a0r, float& a0i, float& a1r, float& a1i) {
    float h = 0.5f * xw;
    float s = __sinf(h), c = __cosf(h);
    float m0 = cst[w * 4 + 0], m1 = cst[w * 4 + 1], m2 = cst[w * 4 + 2], m3 = cst[w * 4 + 3];
    a0r =  m0 * c + m2 * s;
    a0i =  m1 * c + m3 * s;
    a1r = -m2 * c + m0 * s;
    a1i =  m3 * c - m1 * s;
}

// Layer-1 RY gate as fast-Givens on packed {re,im}: a' = a +- t*b
template<int W>
DEVINL void apply_gate(f32x2 (&a2)[16], const float* cst, int lane, const int (&sw)[10]) {
    constexpr GC gc = CC.g[10 + W];
    float tt = csw(cst[40 + W], sw[W]);
    f32x2 tv; tv.x = tt; tv.y = tt;
    f32x2 b2[16];
    #pragma unroll
    for (int r = 0; r < 16; ++r) {
        f32x2 s = a2[r ^ gc.regXor];
        b2[r].x = fetch<gc.laneXor>(s.x, lane);
        b2[r].y = fetch<gc.laneXor>(s.y, lane);
    }
    #pragma unroll
    for (int r = 0; r < 16; ++r) {
        const bool sR = __builtin_popcount(unsigned(gc.rowR & r)) & 1;
        if (sR) a2[r] = a2[r] + tv * b2[r];   // -> v_pk_fma_f32
        else    a2[r] = a2[r] - tv * b2[r];
    }
}

__global__ __launch_bounds__(256) void qsim(const float* __restrict__ x,
                                            float* __restrict__ out, int B) {
    const float* cst = g_cst;
    int lane = threadIdx.x & 63;
    int b = __builtin_amdgcn_readfirstlane(blockIdx.x * 4 + (threadIdx.x >> 6));
    if (b >= B) return;
    const float* xb = x + b * 10;

    // ---- lane-parity sign words for the layer-1 rows (bit 31 = sign)
    int l = lane;
    int p48 = (l >> 4) ^ (l >> 5);
    int p56 = p48 ^ (l >> 3);
    int p60 = p56 ^ (l >> 2);
    int p62 = p60 ^ (l >> 1);
    int p63 = p62 ^ l;
    int p31 = p63 ^ (l >> 5);
    int s48 = p48 << 31, s56 = p56 << 31, s60 = p60 << 31;
    int s62 = p62 << 31, s63 = p63 << 31, s31 = p31 << 31;
    int sw[10] = { s31, s48, s56, s60, s62, s63, s63, s63, s63, s63 };

    // ---- reg-wire factors -> t01 (wires 9,8 = reg bits 0,1), t23 (wires 7,6)
    float t01r[4], t01i[4], t23r[4], t23i[4];
    {
        float a0r, a0i, a1r, a1i, b0r, b0i, b1r, b1i;
        wf(cst, xb[9], 9, a0r, a0i, a1r, a1i);
        wf(cst, xb[8], 8, b0r, b0i, b1r, b1i);
        t01r[0] = a0r * b0r - a0i * b0i;  t01i[0] = a0r * b0i + a0i * b0r;
        t01r[1] = a1r * b0r - a1i * b0i;  t01i[1] = a1r * b0i + a1i * b0r;
        t01r[2] = a0r * b1r - a0i * b1i;  t01i[2] = a0r * b1i + a0i * b1r;
        t01r[3] = a1r * b1r - a1i * b1i;  t01i[3] = a1r * b1i + a1i * b1r;
        wf(cst, xb[7], 7, a0r, a0i, a1r, a1i);
        wf(cst, xb[6], 6, b0r, b0i, b1r, b1i);
        t23r[0] = a0r * b0r - a0i * b0i;  t23i[0] = a0r * b0i + a0i * b0r;
        t23r[1] = a1r * b0r - a1i * b0i;  t23i[1] = a1r * b0i + a1i * b0r;
        t23r[2] = a0r * b1r - a0i * b1i;  t23i[2] = a0r * b1i + a0i * b1r;
        t23r[3] = a1r * b1r - a1i * b1i;  t23i[3] = a1r * b1i + a1i * b1r;
    }

    // ---- lane factor: E_A (phases of w1..5) * RY cos-product * wire factors
    float lfr, lfi;
    {
        float ear = cst[50 + 1 * 2], eai = csw(cst[50 + 1 * 2 + 1], sw[1]);
        #pragma unroll
        for (int w = 2; w <= 5; ++w) {
            float er = cst[50 + w * 2], ei = csw(cst[50 + w * 2 + 1], sw[w]);
            float nr = ear * er - eai * ei;
            float ni = ear * ei + eai * er;
            ear = nr; eai = ni;
        }
        float sc = cst[70];
        lfr = ear * sc; lfi = eai * sc;
        #pragma unroll
        for (int jj = 0; jj < 6; ++jj) {
            int w = 5 - jj;                       // lane bit jj <-> wire 5-jj
            float a0r, a0i, a1r, a1i;
            wf(cst, xb[w], w, a0r, a0i, a1r, a1i);
            int bit = (lane >> jj) & 1;
            float pr = bit ? a1r : a0r;
            float pi = bit ? a1i : a0i;
            float nr = lfr * pr - lfi * pi;
            float ni = lfr * pi + lfi * pr;
            lfr = nr; lfi = ni;
        }
    }

    // ---- fold w6/w7 phases into t23:  P = E6*E7, Q = E6*conj(E7)
    float e6r = cst[50 + 6 * 2], e6i = csw(cst[50 + 6 * 2 + 1], sw[6]);
    float e7r = cst[50 + 7 * 2], e7i = csw(cst[50 + 7 * 2 + 1], sw[7]);
    float Pr_ = e6r * e7r - e6i * e7i, Pi_ = e6r * e7i + e6i * e7r;
    float Qr_ = e6r * e7r + e6i * e7i, Qi_ = e6i * e7r - e6r * e7i;
    float t23pr[4], t23pi[4];
    t23pr[0] = t23r[0] * Pr_ - t23i[0] * Pi_;  t23pi[0] = t23r[0] * Pi_ + t23i[0] * Pr_;
    t23pr[1] = t23r[1] * Qr_ - t23i[1] * Qi_;  t23pi[1] = t23r[1] * Qi_ + t23i[1] * Qr_;
    t23pr[2] = t23r[2] * Pr_ + t23i[2] * Pi_;  t23pi[2] = t23i[2] * Pr_ - t23r[2] * Pi_;
    t23pr[3] = t23r[3] * Qr_ + t23i[3] * Qi_;  t23pi[3] = t23i[3] * Qr_ - t23r[3] * Qi_;

    // ---- w8 + (w0*w9) phases:  G0 = E8*EB, G1 = E8*conj(EB), EB = E0*E9
    float e0r = cst[50 + 0 * 2], e0i = csw(cst[50 + 0 * 2 + 1], sw[0]);
    float e9r = cst[50 + 9 * 2], e9i = csw(cst[50 + 9 * 2 + 1], sw[9]);
    float e8r = cst[50 + 8 * 2], e8i = csw(cst[50 + 8 * 2 + 1], sw[8]);
    float ebr = e0r * e9r - e0i * e9i, ebi = e0r * e9i + e0i * e9r;
    float G0r = e8r * ebr - e8i * ebi, G0i = e8r * ebi + e8i * ebr;
    float G1r = e8r * ebr + e8i * ebi, G1i = e8i * ebr - e8r * ebi;

    // ---- g4 = lf * t01 ; amps = (g4 (x) t23p) * G(r)   (packed {re,im})
    float g4r[4], g4i[4];
    #pragma unroll
    for (int v = 0; v < 4; ++v) {
        g4r[v] = lfr * t01r[v] - lfi * t01i[v];
        g4i[v] = lfr * t01i[v] + lfi * t01r[v];
    }
    f32x2 a2[16];
    #pragma unroll
    for (int r = 0; r < 16; ++r) {
        float tr = g4r[r & 3] * t23pr[r >> 2] - g4i[r & 3] * t23pi[r >> 2];
        float ti = g4r[r & 3] * t23pi[r >> 2] + g4i[r & 3] * t23pr[r >> 2];
        float gr = (r & 1) ? G1r : G0r;                        // compile-time
        float gi = (r & 1) ? G1i : G0i;
        if (__builtin_popcount(unsigned(r & 14)) & 1) gi = -gi; // conj, compile-time
        a2[r].x = tr * gr - ti * gi;
        a2[r].y = tr * gi + ti * gr;
    }

    // ---- layer-1 RY gates; commuting, interleaved LDS-gate / VALU-gate
    apply_gate<1>(a2, cst, lane, sw);   // xor24  swizzle
    apply_gate<4>(a2, cst, lane, sw);   // xor3   DPP
    apply_gate<2>(a2, cst, lane, sw);   // xor12  swizzle
    apply_gate<5>(a2, cst, lane, sw);   // xor1   DPP (reg^8)
    apply_gate<3>(a2, cst, lane, sw);   // xor6   swizzle
    apply_gate<6>(a2, cst, lane, sw);   // reg-local (reg^12)
    apply_gate<0>(a2, cst, lane, sw);   // xor48  permlane32+16
    apply_gate<7>(a2, cst, lane, sw);   // reg-local (reg^6)
    apply_gate<9>(a2, cst, lane, sw);   // xor48  permlane32+16 (reg^1)
    apply_gate<8>(a2, cst, lane, sw);   // reg-local (reg^3)

    // ---- probabilities + reg-WHT stages 1,2,4 (last stage pruned into e[q])
    float wv[16];
    #pragma unroll
    for (int r = 0; r < 16; ++r) wv[r] = a2[r].x * a2[r].x + a2[r].y * a2[r].y;
    #pragma unroll
    for (int bS = 1; bS < 8; bS <<= 1) {
        #pragma unroll
        for (int r = 0; r < 16; ++r) {
            if (!(r & bS)) {
                float xv = wv[r], yv = wv[r | bS];
                wv[r]      = xv + yv;
                wv[r | bS] = xv - yv;
            }
        }
    }

    float e[10];
    #pragma unroll
    for (int q = 0; q < 10; ++q) {
        const int R = CC.sgnR[q];
        float num = (R & 8) ? (wv[R ^ 8] - wv[R]) : (wv[R] + wv[R ^ 8]);
        int slq = __popc(unsigned(lane & CC.sgnL[q])) & 1;
        e[q] = csw(num, slq << 31);
    }

    // ---- lane reduction: DPP quad-reduce all 10, pack to 3 by quad-slot,
    //      then xor4/8 swizzle + xor16/32 permlane-sum
    #pragma unroll
    for (int q = 0; q < 10; ++q) {
        e[q] += fetch<1>(e[q], lane);
        e[q] += fetch<2>(e[q], lane);
    }
    int s = lane & 3;
    bool s1 = (s & 1) != 0, s2 = (s & 2) != 0;
    float v0 = s1 ? e[1] : e[0];
    float u0 = s1 ? e[3] : e[2];
    v0 = s2 ? u0 : v0;
    float v1 = s1 ? e[5] : e[4];
    float u1 = s1 ? e[7] : e[6];
    v1 = s2 ? u1 : v1;
    float v2 = s1 ? e[9] : e[8];

    v0 += fetch<4>(v0, lane);  v1 += fetch<4>(v1, lane);  v2 += fetch<4>(v2, lane);
    v0 += fetch<8>(v0, lane);  v1 += fetch<8>(v1, lane);  v2 += fetch<8>(v2, lane);
    v0 = bsum16(v0, lane);     v1 = bsum16(v1, lane);     v2 = bsum16(v2, lane);
    v0 = bsum32(v0, lane);     v1 = bsum32(v1, lane);     v2 = bsum32(v2, lane);

    // lane q holds full sum of e[q] in v_{q>>2} (slot = q&3 matches lane&3)
    float vo = v0;
    int hi = lane >> 2;
    vo = (hi == 1) ? v1 : vo;
    vo = (hi == 2) ? v2 : vo;
    if (lane < 10) out[b * 10 + lane] = vo;
}

extern "C" void kernel_launch(void* const* d_in, const int* in_sizes, int n_in,
                              void* d_out, int out_size, void* d_ws, size_t ws_size,
                              hipStream_t stream) {
    const float* x  = (const float*)d_in[0];
    const float* qw = (const float*)d_in[1];
    float* out = (float*)d_out;
    int B = in_sizes[0] / 10;
    int blocks = (B + 3) / 4;   // 4 samples (waves) per 256-thread block
    hipLaunchKernelGGL(qprep, dim3(1), dim3(64), 0, stream, qw);
    hipLaunchKernelGGL(qsim, dim3(blocks), dim3(256), 0, stream, x, out, B);
}

// Round 5
// 86.880 us; speedup vs baseline: 1.1635x; 1.1635x over previous
//
#include <hip/hip_runtime.h>

#define DEVINL __device__ __forceinline__

typedef float f32x2 __attribute__((ext_vector_type(2)));

// ---------------------------------------------------------------------------
// Compile-time circuit constants via GF(2) linear-map tracking.
// Physical index p (10 bits): bits 9..4 = lane (6 bits), bits 3..0 = reg (4).
// Logical amplitude index a = A * p (A over GF(2)).  CNOT(c,t) => A row update
// with NO data movement.  A 1q gate on wire w pairs p with p ^ (A^{-1} e_{9-w});
// side bit = parity(row_{9-w}(A) & p).
//
// Round-5 == Round-4 resubmitted (R4 bench was an infra failure, no data).
// R4 rationale (from R3 post-mortem: VALU work grew 55% because the xor48
// permlane partner-recovery chain costs 6 VALU/value = 384 VALU/wave and
// serializes; LDS pipe meanwhile sits at ~30% of its R1 load):
//  * xor48 gates (w0,w9) -> back to ds_bpermute: 64 LDS ops replace 384
//    VALU ops.  LDS total ~166 ops/wave -- still under the VALU time, so
//    it hides.  xor1/3 stay on DPP (1 VALU op, cheaper than LDS).
//  * Gate update forced to v_pk_fma_f32 via inline asm (plain packed form,
//    no modifiers): 16 issues/gate guaranteed; sign pre-folded into a
//    negated broadcast so both +-t cases are a bare pk_fma.
//  * Constants stay in __device__ g_cst (scalar-cache loads, SMEM pipe).
//  * Reduce stays: DPP quad-reduce, slot-pack to 3, swizzle xor4/8,
//    permlane-sum xor16/32 (exact).
//  * Gates commute: schedule alternates LDS-fetch gates with DPP/local
//    gates so both pipes stay fed.
// ---------------------------------------------------------------------------
struct GC { int laneXor, regXor, rowL, rowR; };
struct Circ { GC g[20]; int sgnL[10], sgnR[10]; };

constexpr Circ build_circ() {
    Circ c{};
    unsigned A[10] = {};
    for (int i = 0; i < 10; ++i) A[i] = 1u << i;
    for (int w = 0; w < 10; ++w) {
        int pos = 9 - w;
        unsigned m = 1u << pos;
        c.g[w] = GC{ int(m >> 4), int(m & 15u), int(m >> 4), int(m & 15u) };
    }
    // layer 0 CNOT ring, range r=1
    for (int q = 0; q < 10; ++q) { int pc = 9 - q, pt = 9 - ((q + 1) % 10); A[pt] ^= A[pc]; }
    // invert A over GF(2)
    unsigned M[10] = {}, Inv[10] = {};
    for (int i = 0; i < 10; ++i) { M[i] = A[i]; Inv[i] = 1u << i; }
    for (int col = 0; col < 10; ++col) {
        int piv = col;
        while (!((M[piv] >> col) & 1u)) ++piv;
        unsigned tm = M[col]; M[col] = M[piv]; M[piv] = tm;
        unsigned ti = Inv[col]; Inv[col] = Inv[piv]; Inv[piv] = ti;
        for (int r = 0; r < 10; ++r)
            if (r != col && ((M[r] >> col) & 1u)) { M[r] ^= M[col]; Inv[r] ^= Inv[col]; }
    }
    // layer 1 Rot gates: m = A^{-1} e_pos, row = A[pos]
    for (int w = 0; w < 10; ++w) {
        int pos = 9 - w;
        unsigned m = 0;
        for (int i = 0; i < 10; ++i) m |= ((Inv[i] >> pos) & 1u) << i;
        unsigned row = A[pos];
        c.g[10 + w] = GC{ int(m >> 4), int(m & 15u), int(row >> 4), int(row & 15u) };
    }
    // layer 1 CNOT ring, range r=2
    for (int q = 0; q < 10; ++q) { int pc = 9 - q, pt = 9 - ((q + 2) % 10); A[pt] ^= A[pc]; }
    for (int q = 0; q < 10; ++q) { unsigned row = A[9 - q]; c.sgnL[q] = int(row >> 4); c.sgnR[q] = int(row & 15u); }
    return c;
}

constexpr Circ CC = build_circ();

// Phase-folding below relies on exactly these rows.
static_assert(CC.g[10].rowL == 31 && CC.g[10].rowR == 15, "w0 row");
static_assert(CC.g[11].rowL == 48 && CC.g[11].rowR == 0,  "w1 row");
static_assert(CC.g[12].rowL == 56 && CC.g[12].rowR == 0,  "w2 row");
static_assert(CC.g[13].rowL == 60 && CC.g[13].rowR == 0,  "w3 row");
static_assert(CC.g[14].rowL == 62 && CC.g[14].rowR == 0,  "w4 row");
static_assert(CC.g[15].rowL == 63 && CC.g[15].rowR == 0,  "w5 row");
static_assert(CC.g[16].rowL == 63 && CC.g[16].rowR == 8,  "w6 row");
static_assert(CC.g[17].rowL == 63 && CC.g[17].rowR == 12, "w7 row");
static_assert(CC.g[18].rowL == 63 && CC.g[18].rowR == 14, "w8 row");
static_assert(CC.g[19].rowL == 63 && CC.g[19].rowR == 15, "w9 row");
// Gate laneXor inventory this schedule depends on (A rows are suffix-masks
// after the r=1 ring, so m = e_{pos-1}^e_pos except at the ends).
static_assert(CC.g[10].laneXor == 48 && CC.g[10].regXor == 0, "w0 m");
static_assert(CC.g[11].laneXor == 24 && CC.g[12].laneXor == 12, "w1/w2 m");
static_assert(CC.g[13].laneXor == 6  && CC.g[14].laneXor == 3,  "w3/w4 m");
static_assert(CC.g[15].laneXor == 1  && CC.g[15].regXor == 8,   "w5 m");
static_assert(CC.g[16].laneXor == 0 && CC.g[16].regXor == 12, "w6 m");
static_assert(CC.g[17].laneXor == 0 && CC.g[17].regXor == 6,  "w7 m");
static_assert(CC.g[18].laneXor == 0 && CC.g[18].regXor == 3,  "w8 m");
static_assert(CC.g[19].laneXor == 48 && CC.g[19].regXor == 1,   "w9 m");

#if __has_builtin(__builtin_amdgcn_permlane32_swap)
#define HAS_PL32 1
#else
#define HAS_PL32 0
#endif
#if __has_builtin(__builtin_amdgcn_permlane16_swap)
#define HAS_PL16 1
#else
#define HAS_PL16 0
#endif

// sign-word xor: sw has the sign in bit 31 (or is 0)
DEVINL float csw(float v, int sw) {
    return __int_as_float(__float_as_int(v) ^ sw);
}

// butterfly sums (v + v[lane^N]) for the reduction — exact, convention-indep:
// same-reg permlaneN_swap returns the two half-duplicated patterns; their sum
// is the pair-sum in every lane.
DEVINL float bsum16(float v, int lane) {
#if HAS_PL16
    auto r = __builtin_amdgcn_permlane16_swap(__float_as_int(v), __float_as_int(v), false, false);
    return __int_as_float(r[0]) + __int_as_float(r[1]);
#else
    return v + __int_as_float(__builtin_amdgcn_ds_swizzle(__float_as_int(v), 0x1F | (16 << 10)));
#endif
}
DEVINL float bsum32(float v, int lane) {
#if HAS_PL32
    auto r = __builtin_amdgcn_permlane32_swap(__float_as_int(v), __float_as_int(v), false, false);
    return __int_as_float(r[0]) + __int_as_float(r[1]);
#else
    return v + __int_as_float(__builtin_amdgcn_ds_bpermute((lane ^ 32) << 2, __float_as_int(v)));
#endif
}

// lane-xor fetch: DPP (VALU) for 1..3, ds_swizzle for <32, ds_bpermute else
template<int XOR>
DEVINL float fetch(float v, int lane) {
    if constexpr (XOR == 0)      return v;
    else if constexpr (XOR == 1) return __int_as_float(__builtin_amdgcn_update_dpp(0, __float_as_int(v), 0xB1, 0xF, 0xF, true));
    else if constexpr (XOR == 2) return __int_as_float(__builtin_amdgcn_update_dpp(0, __float_as_int(v), 0x4E, 0xF, 0xF, true));
    else if constexpr (XOR == 3) return __int_as_float(__builtin_amdgcn_update_dpp(0, __float_as_int(v), 0x1B, 0xF, 0xF, true));
    else if constexpr (XOR < 32) return __int_as_float(__builtin_amdgcn_ds_swizzle(__float_as_int(v), 0x1F | (XOR << 10)));
    else return __int_as_float(__builtin_amdgcn_ds_bpermute((lane ^ XOR) << 2, __float_as_int(v)));
}

// forced packed FMA: a = t*b + a  (plain packed form, no modifiers)
DEVINL void pk_fma_acc(f32x2& a, f32x2 t, f32x2 b) {
    asm("v_pk_fma_f32 %0, %1, %2, %0" : "+v"(a) : "v"(t), "v"(b));
}

// ---------------------------------------------------------------------------
// Constants, computed once by qprep:
// [0..39]  layer-0 Rot mats (u00r,u00i,u01r,u01i per wire)
// [40..49] layer-1 tan(th/2) per wire
// [50..69] layer-1 (cos(phi/2), -sin(phi/2)) per wire
// [70]     prod_w cos(th_w/2)
// ---------------------------------------------------------------------------
__device__ __attribute__((aligned(16))) float g_cst[80];

__global__ void qprep(const float* __restrict__ qw) {
    int g = threadIdx.x;
    if (g < 10) {
        float phi = qw[g * 3 + 0], th = qw[g * 3 + 1], om = qw[g * 3 + 2];
        float c = cosf(0.5f * th), s = sinf(0.5f * th);
        float apo = 0.5f * (phi + om), amo = 0.5f * (phi - om);
        g_cst[g * 4 + 0] =  cosf(apo) * c;
        g_cst[g * 4 + 1] = -sinf(apo) * c;
        g_cst[g * 4 + 2] = -cosf(amo) * s;
        g_cst[g * 4 + 3] = -sinf(amo) * s;
    } else if (g < 20) {
        int w = g - 10;
        float phi = qw[g * 3 + 0], th = qw[g * 3 + 1];
        float c = cosf(0.5f * th), s = sinf(0.5f * th);
        g_cst[40 + w] = s / c;
        g_cst[50 + w * 2 + 0] =  cosf(0.5f * phi);
        g_cst[50 + w * 2 + 1] = -sinf(0.5f * phi);
    } else if (g == 20) {
        float p = 1.f;
        for (int w = 0; w < 10; ++w) p *= cosf(0.5f * qw[(10 + w) * 3 + 1]);
        g_cst[70] = p;
    }
}

// per-wire embedding factor: |0> --RY(x)--> --Rot(layer0)--> (a0, a1)
DEVINL void wf(const float* cst, float xw, int w,
               float& a0r, float& a0i, float& a1r, float& a1i) {
    float h = 0.5f * xw;
    float s = __sinf(h), c = __cosf(h);
    float m0 = cst[w * 4 + 0], m1 = cst[w * 4 + 1], m2 = cst[w * 4 + 2], m3 = cst[w * 4 + 3];
    a0r =  m0 * c + m2 * s;
    a0i =  m1 * c + m3 * s;
    a1r = -m2 * c + m0 * s;
    a1i =  m3 * c - m1 * s;
}

// Layer-1 RY gate as fast-Givens on packed {re,im}: a' = a +- t*b
template<int W>
DEVINL void apply_gate(f32x2 (&a2)[16], const float* cst, int lane, const int (&sw)[10]) {
    constexpr GC gc = CC.g[10 + W];
    float tt = csw(cst[40 + W], sw[W]);
    f32x2 tp; tp.x = tt;  tp.y = tt;
    f32x2 tn; tn.x = -tt; tn.y = -tt;
    f32x2 b2[16];
    #pragma unroll
    for (int r = 0; r < 16; ++r) {
        f32x2 s = a2[r ^ gc.regXor];
        b2[r].x = fetch<gc.laneXor>(s.x, lane);
        b2[r].y = fetch<gc.laneXor>(s.y, lane);
    }
    #pragma unroll
    for (int r = 0; r < 16; ++r) {
        const bool sR = __builtin_popcount(unsigned(gc.rowR & r)) & 1;
        pk_fma_acc(a2[r], sR ? tp : tn, b2[r]);   // compile-time select
    }
}

__global__ __launch_bounds__(256) void qsim(const float* __restrict__ x,
                                            float* __restrict__ out, int B) {
    const float* cst = g_cst;
    int lane = threadIdx.x & 63;
    int b = __builtin_amdgcn_readfirstlane(blockIdx.x * 4 + (threadIdx.x >> 6));
    if (b >= B) return;
    const float* xb = x + b * 10;

    // ---- lane-parity sign words for the layer-1 rows (bit 31 = sign)
    int l = lane;
    int p48 = (l >> 4) ^ (l >> 5);
    int p56 = p48 ^ (l >> 3);
    int p60 = p56 ^ (l >> 2);
    int p62 = p60 ^ (l >> 1);
    int p63 = p62 ^ l;
    int p31 = p63 ^ (l >> 5);
    int s48 = p48 << 31, s56 = p56 << 31, s60 = p60 << 31;
    int s62 = p62 << 31, s63 = p63 << 31, s31 = p31 << 31;
    int sw[10] = { s31, s48, s56, s60, s62, s63, s63, s63, s63, s63 };

    // ---- reg-wire factors -> t01 (wires 9,8 = reg bits 0,1), t23 (wires 7,6)
    float t01r[4], t01i[4], t23r[4], t23i[4];
    {
        float a0r, a0i, a1r, a1i, b0r, b0i, b1r, b1i;
        wf(cst, xb[9], 9, a0r, a0i, a1r, a1i);
        wf(cst, xb[8], 8, b0r, b0i, b1r, b1i);
        t01r[0] = a0r * b0r - a0i * b0i;  t01i[0] = a0r * b0i + a0i * b0r;
        t01r[1] = a1r * b0r - a1i * b0i;  t01i[1] = a1r * b0i + a1i * b0r;
        t01r[2] = a0r * b1r - a0i * b1i;  t01i[2] = a0r * b1i + a0i * b1r;
        t01r[3] = a1r * b1r - a1i * b1i;  t01i[3] = a1r * b1i + a1i * b1r;
        wf(cst, xb[7], 7, a0r, a0i, a1r, a1i);
        wf(cst, xb[6], 6, b0r, b0i, b1r, b1i);
        t23r[0] = a0r * b0r - a0i * b0i;  t23i[0] = a0r * b0i + a0i * b0r;
        t23r[1] = a1r * b0r - a1i * b0i;  t23i[1] = a1r * b0i + a1i * b0r;
        t23r[2] = a0r * b1r - a0i * b1i;  t23i[2] = a0r * b1i + a0i * b1r;
        t23r[3] = a1r * b1r - a1i * b1i;  t23i[3] = a1r * b1i + a1i * b1r;
    }

    // ---- lane factor: E_A (phases of w1..5) * RY cos-product * wire factors
    float lfr, lfi;
    {
        float ear = cst[50 + 1 * 2], eai = csw(cst[50 + 1 * 2 + 1], sw[1]);
        #pragma unroll
        for (int w = 2; w <= 5; ++w) {
            float er = cst[50 + w * 2], ei = csw(cst[50 + w * 2 + 1], sw[w]);
            float nr = ear * er - eai * ei;
            float ni = ear * ei + eai * er;
            ear = nr; eai = ni;
        }
        float sc = cst[70];
        lfr = ear * sc; lfi = eai * sc;
        #pragma unroll
        for (int jj = 0; jj < 6; ++jj) {
            int w = 5 - jj;                       // lane bit jj <-> wire 5-jj
            float a0r, a0i, a1r, a1i;
            wf(cst, xb[w], w, a0r, a0i, a1r, a1i);
            int bit = (lane >> jj) & 1;
            float pr = bit ? a1r : a0r;
            float pi = bit ? a1i : a0i;
            float nr = lfr * pr - lfi * pi;
            float ni = lfr * pi + lfi * pr;
            lfr = nr; lfi = ni;
        }
    }

    // ---- fold w6/w7 phases into t23:  P = E6*E7, Q = E6*conj(E7)
    float e6r = cst[50 + 6 * 2], e6i = csw(cst[50 + 6 * 2 + 1], sw[6]);
    float e7r = cst[50 + 7 * 2], e7i = csw(cst[50 + 7 * 2 + 1], sw[7]);
    float Pr_ = e6r * e7r - e6i * e7i, Pi_ = e6r * e7i + e6i * e7r;
    float Qr_ = e6r * e7r + e6i * e7i, Qi_ = e6i * e7r - e6r * e7i;
    float t23pr[4], t23pi[4];
    t23pr[0] = t23r[0] * Pr_ - t23i[0] * Pi_;  t23pi[0] = t23r[0] * Pi_ + t23i[0] * Pr_;
    t23pr[1] = t23r[1] * Qr_ - t23i[1] * Qi_;  t23pi[1] = t23r[1] * Qi_ + t23i[1] * Qr_;
    t23pr[2] = t23r[2] * Pr_ + t23i[2] * Pi_;  t23pi[2] = t23i[2] * Pr_ - t23r[2] * Pi_;
    t23pr[3] = t23r[3] * Qr_ + t23i[3] * Qi_;  t23pi[3] = t23i[3] * Qr_ - t23r[3] * Qi_;

    // ---- w8 + (w0*w9) phases:  G0 = E8*EB, G1 = E8*conj(EB), EB = E0*E9
    float e0r = cst[50 + 0 * 2], e0i = csw(cst[50 + 0 * 2 + 1], sw[0]);
    float e9r = cst[50 + 9 * 2], e9i = csw(cst[50 + 9 * 2 + 1], sw[9]);
    float e8r = cst[50 + 8 * 2], e8i = csw(cst[50 + 8 * 2 + 1], sw[8]);
    float ebr = e0r * e9r - e0i * e9i, ebi = e0r * e9i + e0i * e9r;
    float G0r = e8r * ebr - e8i * ebi, G0i = e8r * ebi + e8i * ebr;
    float G1r = e8r * ebr + e8i * ebi, G1i = e8i * ebr - e8r * ebi;

    // ---- g4 = lf * t01 ; amps = (g4 (x) t23p) * G(r)   (packed {re,im})
    float g4r[4], g4i[4];
    #pragma unroll
    for (int v = 0; v < 4; ++v) {
        g4r[v] = lfr * t01r[v] - lfi * t01i[v];
        g4i[v] = lfr * t01i[v] + lfi * t01r[v];
    }
    f32x2 a2[16];
    #pragma unroll
    for (int r = 0; r < 16; ++r) {
        float tr = g4r[r & 3] * t23pr[r >> 2] - g4i[r & 3] * t23pi[r >> 2];
        float ti = g4r[r & 3] * t23pi[r >> 2] + g4i[r & 3] * t23pr[r >> 2];
        float gr = (r & 1) ? G1r : G0r;                        // compile-time
        float gi = (r & 1) ? G1i : G0i;
        if (__builtin_popcount(unsigned(r & 14)) & 1) gi = -gi; // conj, compile-time
        a2[r].x = tr * gr - ti * gi;
        a2[r].y = tr * gi + ti * gr;
    }

    // ---- layer-1 RY gates; commuting, scheduled LDS-gate / VALU-gate
    apply_gate<1>(a2, cst, lane, sw);   // xor24  swizzle
    apply_gate<4>(a2, cst, lane, sw);   // xor3   DPP
    apply_gate<2>(a2, cst, lane, sw);   // xor12  swizzle
    apply_gate<6>(a2, cst, lane, sw);   // reg-local (reg^12)
    apply_gate<3>(a2, cst, lane, sw);   // xor6   swizzle
    apply_gate<5>(a2, cst, lane, sw);   // xor1   DPP (reg^8)
    apply_gate<0>(a2, cst, lane, sw);   // xor48  bpermute
    apply_gate<7>(a2, cst, lane, sw);   // reg-local (reg^6)
    apply_gate<9>(a2, cst, lane, sw);   // xor48  bpermute (reg^1)
    apply_gate<8>(a2, cst, lane, sw);   // reg-local (reg^3)

    // ---- probabilities + reg-WHT stages 1,2,4 (last stage pruned into e[q])
    float wv[16];
    #pragma unroll
    for (int r = 0; r < 16; ++r) wv[r] = a2[r].x * a2[r].x + a2[r].y * a2[r].y;
    #pragma unroll
    for (int bS = 1; bS < 8; bS <<= 1) {
        #pragma unroll
        for (int r = 0; r < 16; ++r) {
            if (!(r & bS)) {
                float xv = wv[r], yv = wv[r | bS];
                wv[r]      = xv + yv;
                wv[r | bS] = xv - yv;
            }
        }
    }

    float e[10];
    #pragma unroll
    for (int q = 0; q < 10; ++q) {
        const int R = CC.sgnR[q];
        float num = (R & 8) ? (wv[R ^ 8] - wv[R]) : (wv[R] + wv[R ^ 8]);
        int slq = __popc(unsigned(lane & CC.sgnL[q])) & 1;
        e[q] = csw(num, slq << 31);
    }

    // ---- lane reduction: DPP quad-reduce all 10, pack to 3 by quad-slot,
    //      then xor4/8 swizzle + xor16/32 permlane-sum
    #pragma unroll
    for (int q = 0; q < 10; ++q) {
        e[q] += fetch<1>(e[q], lane);
        e[q] += fetch<2>(e[q], lane);
    }
    int s = lane & 3;
    bool s1 = (s & 1) != 0, s2 = (s & 2) != 0;
    float v0 = s1 ? e[1] : e[0];
    float u0 = s1 ? e[3] : e[2];
    v0 = s2 ? u0 : v0;
    float v1 = s1 ? e[5] : e[4];
    float u1 = s1 ? e[7] : e[6];
    v1 = s2 ? u1 : v1;
    float v2 = s1 ? e[9] : e[8];

    v0 += fetch<4>(v0, lane);  v1 += fetch<4>(v1, lane);  v2 += fetch<4>(v2, lane);
    v0 += fetch<8>(v0, lane);  v1 += fetch<8>(v1, lane);  v2 += fetch<8>(v2, lane);
    v0 = bsum16(v0, lane);     v1 = bsum16(v1, lane);     v2 = bsum16(v2, lane);
    v0 = bsum32(v0, lane);     v1 = bsum32(v1, lane);     v2 = bsum32(v2, lane);

    // lane q holds full sum of e[q] in v_{q>>2} (slot = q&3 matches lane&3)
    float vo = v0;
    int hi = lane >> 2;
    vo = (hi == 1) ? v1 : vo;
    vo = (hi == 2) ? v2 : vo;
    if (lane < 10) out[b * 10 + lane] = vo;
}

extern "C" void kernel_launch(void* const* d_in, const int* in_sizes, int n_in,
                              void* d_out, int out_size, void* d_ws, size_t ws_size,
                              hipStream_t stream) {
    const float* x  = (const float*)d_in[0];
    const float* qw = (const float*)d_in[1];
    float* out = (float*)d_out;
    int B = in_sizes[0] / 10;
    int blocks = (B + 3) / 4;   // 4 samples (waves) per 256-thread block
    hipLaunchKernelGGL(qprep, dim3(1), dim3(64), 0, stream, qw);
    hipLaunchKernelGGL(qsim, dim3(blocks), dim3(256), 0, stream, x, out, B);
}

// Round 6
// 82.091 us; speedup vs baseline: 1.2314x; 1.0583x over previous
//
#include <hip/hip_runtime.h>

#define DEVINL __device__ __forceinline__

typedef float f32x2 __attribute__((ext_vector_type(2)));

// ---------------------------------------------------------------------------
// Compile-time circuit constants via GF(2) linear-map tracking.
// Physical index p (10 bits).  NEW SPLIT (round 6): bits 9..5 = lane bits 4..0
// (5 bits), bits 4..0 = reg (5 bits).  Lane bit 5 = SAMPLE SELECT: each wave
// simulates TWO samples, one per 32-lane half.  All cross-lane ops (swizzle
// bitmode, DPP quad_perm, reduce butterflies <=xor16) confine to 32-halves.
//
// Why (R5 post-mortem): qsim dropped below the 39.6us harness memsets
// (~37us est).  Calibration vs R1 (330 LDS/sample ~ 44.7us, LDS-bound) puts
// R5 at LDS ~22us / VALU ~26us.  Half the VALU is the per-wave prologue
// (wf factors, trig, lane chain, phase folds) serving ONE sample.  2 samples
// per wave halves prologue+epilogue per sample, and the new mask split
// eliminates ds_bpermute entirely (max laneXor = 24 -> all ds_swizzle):
//   gates: swz24 (w0,w9), swz12 (w1), swz6 (w2), DPP3 (w3), DPP1 (w4,reg^16),
//          reg-local (w5,w6,w7,w8).
// Phase folding (re-derived for 5/5 split, rows asserted):
//   w1..w4 (R=0)    -> lane factor E_A
//   w5 (R=16)       -> f5 table (2 entries, bit4)
//   w6 (24), w7(28) -> V^{+-} folded into 8-entry t23(x)f5 table (bits 4,3,2)
//   w8(30)+w9(31)+w0(31) -> per-amp G = par(r&30) ? conj(H[r&1]) : H[r&1],
//                           H0 = E8*EB, H1 = E8*conj(EB), EB = E9*E0
// ---------------------------------------------------------------------------
struct GC { int laneXor, regXor, rowL, rowR; };
struct Circ { GC g[20]; int sgnL[10], sgnR[10]; };

constexpr Circ build_circ() {
    Circ c{};
    unsigned A[10] = {};
    for (int i = 0; i < 10; ++i) A[i] = 1u << i;
    for (int w = 0; w < 10; ++w) {
        int pos = 9 - w;
        unsigned m = 1u << pos;
        c.g[w] = GC{ int(m >> 5), int(m & 31u), int(m >> 5), int(m & 31u) };
    }
    // layer 0 CNOT ring, range r=1
    for (int q = 0; q < 10; ++q) { int pc = 9 - q, pt = 9 - ((q + 1) % 10); A[pt] ^= A[pc]; }
    // invert A over GF(2)
    unsigned M[10] = {}, Inv[10] = {};
    for (int i = 0; i < 10; ++i) { M[i] = A[i]; Inv[i] = 1u << i; }
    for (int col = 0; col < 10; ++col) {
        int piv = col;
        while (!((M[piv] >> col) & 1u)) ++piv;
        unsigned tm = M[col]; M[col] = M[piv]; M[piv] = tm;
        unsigned ti = Inv[col]; Inv[col] = Inv[piv]; Inv[piv] = ti;
        for (int r = 0; r < 10; ++r)
            if (r != col && ((M[r] >> col) & 1u)) { M[r] ^= M[col]; Inv[r] ^= Inv[col]; }
    }
    // layer 1 Rot gates: m = A^{-1} e_pos, row = A[pos]  (5/5 split)
    for (int w = 0; w < 10; ++w) {
        int pos = 9 - w;
        unsigned m = 0;
        for (int i = 0; i < 10; ++i) m |= ((Inv[i] >> pos) & 1u) << i;
        unsigned row = A[pos];
        c.g[10 + w] = GC{ int(m >> 5), int(m & 31u), int(row >> 5), int(row & 31u) };
    }
    // layer 1 CNOT ring, range r=2
    for (int q = 0; q < 10; ++q) { int pc = 9 - q, pt = 9 - ((q + 2) % 10); A[pt] ^= A[pc]; }
    for (int q = 0; q < 10; ++q) { unsigned row = A[9 - q]; c.sgnL[q] = int(row >> 5); c.sgnR[q] = int(row & 31u); }
    return c;
}

constexpr Circ CC = build_circ();

// Phase-folding + schedule below rely on exactly these masks (5/5 split).
static_assert(CC.g[10].laneXor == 24 && CC.g[10].regXor == 0,  "w0 m");
static_assert(CC.g[11].laneXor == 12 && CC.g[11].regXor == 0,  "w1 m");
static_assert(CC.g[12].laneXor == 6  && CC.g[12].regXor == 0,  "w2 m");
static_assert(CC.g[13].laneXor == 3  && CC.g[13].regXor == 0,  "w3 m");
static_assert(CC.g[14].laneXor == 1  && CC.g[14].regXor == 16, "w4 m");
static_assert(CC.g[15].laneXor == 0  && CC.g[15].regXor == 24, "w5 m");
static_assert(CC.g[16].laneXor == 0  && CC.g[16].regXor == 12, "w6 m");
static_assert(CC.g[17].laneXor == 0  && CC.g[17].regXor == 6,  "w7 m");
static_assert(CC.g[18].laneXor == 0  && CC.g[18].regXor == 3,  "w8 m");
static_assert(CC.g[19].laneXor == 24 && CC.g[19].regXor == 1,  "w9 m");
static_assert(CC.g[10].rowL == 15 && CC.g[10].rowR == 31, "w0 row");
static_assert(CC.g[11].rowL == 24 && CC.g[11].rowR == 0,  "w1 row");
static_assert(CC.g[12].rowL == 28 && CC.g[12].rowR == 0,  "w2 row");
static_assert(CC.g[13].rowL == 30 && CC.g[13].rowR == 0,  "w3 row");
static_assert(CC.g[14].rowL == 31 && CC.g[14].rowR == 0,  "w4 row");
static_assert(CC.g[15].rowL == 31 && CC.g[15].rowR == 16, "w5 row");
static_assert(CC.g[16].rowL == 31 && CC.g[16].rowR == 24, "w6 row");
static_assert(CC.g[17].rowL == 31 && CC.g[17].rowR == 28, "w7 row");
static_assert(CC.g[18].rowL == 31 && CC.g[18].rowR == 30, "w8 row");
static_assert(CC.g[19].rowL == 31 && CC.g[19].rowR == 31, "w9 row");

// sign-word xor: sw has the sign in bit 31 (or is 0)
DEVINL float csw(float v, int sw) {
    return __int_as_float(__float_as_int(v) ^ sw);
}

// lane-xor fetch: DPP (VALU) for 1..3, ds_swizzle (xor<32) otherwise.
// ds_swizzle bitmode operates within 32-lane groups -> samples stay separate.
template<int XOR>
DEVINL float fetch(float v, int lane) {
    if constexpr (XOR == 0)      return v;
    else if constexpr (XOR == 1) return __int_as_float(__builtin_amdgcn_update_dpp(0, __float_as_int(v), 0xB1, 0xF, 0xF, true));
    else if constexpr (XOR == 2) return __int_as_float(__builtin_amdgcn_update_dpp(0, __float_as_int(v), 0x4E, 0xF, 0xF, true));
    else if constexpr (XOR == 3) return __int_as_float(__builtin_amdgcn_update_dpp(0, __float_as_int(v), 0x1B, 0xF, 0xF, true));
    else                         return __int_as_float(__builtin_amdgcn_ds_swizzle(__float_as_int(v), 0x1F | (XOR << 10)));
}

// forced packed FMA: a = t*b + a
DEVINL void pk_fma_acc(f32x2& a, f32x2 t, f32x2 b) {
    asm("v_pk_fma_f32 %0, %1, %2, %0" : "+v"(a) : "v"(t), "v"(b));
}

DEVINL f32x2 cmul(f32x2 a, f32x2 b) {
    f32x2 r;
    r.x = a.x * b.x - a.y * b.y;
    r.y = a.x * b.y + a.y * b.x;
    return r;
}

// ---------------------------------------------------------------------------
// Constants, computed once by qprep (wire-indexed; split-agnostic):
// [0..39]  layer-0 Rot mats (u00r,u00i,u01r,u01i per wire)
// [40..49] layer-1 tan(th/2) per wire
// [50..69] layer-1 (cos(phi/2), -sin(phi/2)) per wire
// [70]     prod_w cos(th_w/2)
// ---------------------------------------------------------------------------
__device__ __attribute__((aligned(16))) float g_cst[80];

__global__ void qprep(const float* __restrict__ qw) {
    int g = threadIdx.x;
    if (g < 10) {
        float phi = qw[g * 3 + 0], th = qw[g * 3 + 1], om = qw[g * 3 + 2];
        float c = cosf(0.5f * th), s = sinf(0.5f * th);
        float apo = 0.5f * (phi + om), amo = 0.5f * (phi - om);
        g_cst[g * 4 + 0] =  cosf(apo) * c;
        g_cst[g * 4 + 1] = -sinf(apo) * c;
        g_cst[g * 4 + 2] = -cosf(amo) * s;
        g_cst[g * 4 + 3] = -sinf(amo) * s;
    } else if (g < 20) {
        int w = g - 10;
        float phi = qw[g * 3 + 0], th = qw[g * 3 + 1];
        float c = cosf(0.5f * th), s = sinf(0.5f * th);
        g_cst[40 + w] = s / c;
        g_cst[50 + w * 2 + 0] =  cosf(0.5f * phi);
        g_cst[50 + w * 2 + 1] = -sinf(0.5f * phi);
    } else if (g == 20) {
        float p = 1.f;
        for (int w = 0; w < 10; ++w) p *= cosf(0.5f * qw[(10 + w) * 3 + 1]);
        g_cst[70] = p;
    }
}

// per-wire embedding factor: |0> --RY(x)--> --Rot(layer0)--> (f0, f1)
DEVINL void wf(const float* cst, float xw, int w, f32x2& f0, f32x2& f1) {
    float h = 0.5f * xw;
    float s = __sinf(h), c = __cosf(h);
    float m0 = cst[w * 4 + 0], m1 = cst[w * 4 + 1], m2 = cst[w * 4 + 2], m3 = cst[w * 4 + 3];
    f0.x =  m0 * c + m2 * s;
    f0.y =  m1 * c + m3 * s;
    f1.x = -m2 * c + m0 * s;
    f1.y =  m3 * c - m1 * s;
}

// Layer-1 RY gate as fast-Givens on packed {re,im}: a' = a +- t*b.
// Lane-xor gates: two chunks {0..7,16..23} / {8..15,24..31}, each closed
// under ^regXor (regXor in {0,1,16}) -> stage-then-fma is read-before-write.
// Local gates: pairwise update with one temp.
template<int W>
DEVINL void apply_gate(f32x2 (&a2)[32], const float* cst, int lane, const int (&sw)[10]) {
    constexpr GC gc = CC.g[10 + W];
    float tt = csw(cst[40 + W], sw[W]);
    f32x2 tp; tp.x = tt;  tp.y = tt;
    f32x2 tn; tn.x = -tt; tn.y = -tt;
    if constexpr (gc.laneXor == 0) {
        #pragma unroll
        for (int r = 0; r < 32; ++r) {
            const int r2 = r ^ gc.regXor;
            if (r < r2) {
                f32x2 old = a2[r];
                const bool sR  = __builtin_popcount(unsigned(gc.rowR & r )) & 1;
                const bool sR2 = __builtin_popcount(unsigned(gc.rowR & r2)) & 1;
                pk_fma_acc(a2[r],  sR  ? tp : tn, a2[r2]);
                pk_fma_acc(a2[r2], sR2 ? tp : tn, old);
            }
        }
    } else {
        #pragma unroll
        for (int c = 0; c < 2; ++c) {
            f32x2 b2[16];
            #pragma unroll
            for (int i = 0; i < 16; ++i) {
                const int r = (i & 7) + c * 8 + ((i >> 3) << 4);
                f32x2 s = a2[r ^ gc.regXor];
                b2[i].x = fetch<gc.laneXor>(s.x, lane);
                b2[i].y = fetch<gc.laneXor>(s.y, lane);
            }
            #pragma unroll
            for (int i = 0; i < 16; ++i) {
                const int r = (i & 7) + c * 8 + ((i >> 3) << 4);
                const bool sR = __builtin_popcount(unsigned(gc.rowR & r)) & 1;
                pk_fma_acc(a2[r], sR ? tp : tn, b2[i]);
            }
        }
    }
}

__global__ __launch_bounds__(256) void qsim(const float* __restrict__ x,
                                            float* __restrict__ out, int B) {
    const float* cst = g_cst;
    int lane = threadIdx.x & 63;
    int l5 = lane & 31;                        // 5-bit lane within the sample
    int b = blockIdx.x * 8 + (threadIdx.x >> 5);   // 2 samples/wave, 8/block
    if (b >= B) return;
    const float* xb = x + b * 10;

    // ---- lane-parity sign words over l5 (bit 31 = sign)
    int p24 = (l5 >> 4) ^ (l5 >> 3);
    int p28 = p24 ^ (l5 >> 2);
    int p30 = p28 ^ (l5 >> 1);
    int p31 = p30 ^ l5;
    int p15 = p31 ^ (l5 >> 4);
    int s24 = p24 << 31, s28 = p28 << 31, s30 = p30 << 31,
        s31 = p31 << 31, s15 = p15 << 31;
    int sw_[10] = { s15, s24, s28, s30, s31, s31, s31, s31, s31, s31 };

    // ---- reg-wire tables: bit0=w9, bit1=w8, bit2=w7, bit3=w6, bit4=w5
    f32x2 t01[4], t23[4], f5t[2];
    {
        f32x2 a0, a1, b0, b1;
        wf(cst, xb[9], 9, a0, a1);
        wf(cst, xb[8], 8, b0, b1);
        t01[0] = cmul(a0, b0); t01[1] = cmul(a1, b0);
        t01[2] = cmul(a0, b1); t01[3] = cmul(a1, b1);
        wf(cst, xb[7], 7, a0, a1);
        wf(cst, xb[6], 6, b0, b1);
        t23[0] = cmul(a0, b0); t23[1] = cmul(a1, b0);
        t23[2] = cmul(a0, b1); t23[3] = cmul(a1, b1);
        wf(cst, xb[5], 5, f5t[0], f5t[1]);
    }

    // ---- lane-signed RZ(phi) phase constants E_w = (cos, -+sin)
    f32x2 E0; E0.x = cst[50];      E0.y = csw(cst[51], s15);
    f32x2 E1; E1.x = cst[52];      E1.y = csw(cst[53], s24);
    f32x2 E2; E2.x = cst[54];      E2.y = csw(cst[55], s28);
    f32x2 E3; E3.x = cst[56];      E3.y = csw(cst[57], s30);
    f32x2 E4; E4.x = cst[58];      E4.y = csw(cst[59], s31);
    f32x2 E5; E5.x = cst[60];      E5.y = csw(cst[61], s31);
    f32x2 E6; E6.x = cst[62];      E6.y = csw(cst[63], s31);
    f32x2 E7; E7.x = cst[64];      E7.y = csw(cst[65], s31);
    f32x2 E8; E8.x = cst[66];      E8.y = csw(cst[67], s31);
    f32x2 E9; E9.x = cst[68];      E9.y = csw(cst[69], s31);

    // ---- lane factor: E_A (w1..w4) * cos-product * lane-wire factors
    f32x2 lf;
    {
        f32x2 ea = cmul(cmul(E1, E2), cmul(E3, E4));
        float sc = cst[70];
        lf.x = ea.x * sc; lf.y = ea.y * sc;
        #pragma unroll
        for (int jj = 0; jj < 5; ++jj) {
            int w = 4 - jj;                    // lane bit jj <-> wire 4-jj
            f32x2 f0, f1;
            wf(cst, xb[w], w, f0, f1);
            int bit = (l5 >> jj) & 1;
            f32x2 p; p.x = bit ? f1.x : f0.x; p.y = bit ? f1.y : f0.y;
            lf = cmul(lf, p);
        }
    }

    // ---- fold w5 phase into f5 (bit4); build V/H phase products
    f32x2 f5p[2];
    f5p[0] = cmul(f5t[0], E5);
    { f32x2 e5c; e5c.x = E5.x; e5c.y = -E5.y; f5p[1] = cmul(f5t[1], e5c); }
    f32x2 V00 = cmul(E6, E7);
    f32x2 V01; { f32x2 e7c; e7c.x = E7.x; e7c.y = -E7.y; V01 = cmul(E6, e7c); }
    f32x2 EB = cmul(E9, E0);
    f32x2 H0 = cmul(E8, EB);
    f32x2 H1; { f32x2 ebc; ebc.x = EB.x; ebc.y = -EB.y; H1 = cmul(E8, ebc); }

    // ---- tf[8] = t23[j&3] * f5p[j>>2] * V^{s6,s7}   (j = bits 4,3,2 of r)
    f32x2 tf[8];
    #pragma unroll
    for (int j = 0; j < 8; ++j) {
        f32x2 tA = cmul(t23[j & 3], f5p[j >> 2]);
        const int s6 = ((j >> 2) ^ (j >> 1)) & 1;
        const int s7 = s6 ^ (j & 1);
        f32x2 V;
        V.x = s6 ? (s7 ? V00.x : V01.x) : (s7 ? V01.x : V00.x);
        V.y = s6 ? -(s7 ? V00.y : V01.y) : (s7 ? V01.y : V00.y);
        tf[j] = cmul(tA, V);
    }

    // ---- g4 = lf * t01 ; amps = (g4 (x) tf) * G(r)
    f32x2 g4[4];
    #pragma unroll
    for (int v = 0; v < 4; ++v) g4[v] = cmul(lf, t01[v]);
    f32x2 a2[32];
    #pragma unroll
    for (int r = 0; r < 32; ++r) {
        f32x2 t = cmul(g4[r & 3], tf[(r >> 2) & 7]);
        f32x2 G;
        G.x = (r & 1) ? H1.x : H0.x;
        G.y = (r & 1) ? H1.y : H0.y;
        if (__builtin_popcount(unsigned(r & 30)) & 1) G.y = -G.y;  // conj
        a2[r] = cmul(t, G);
    }

    // ---- layer-1 RY gates; commuting, interleaved swizzle/DPP/local
    apply_gate<0>(a2, cst, lane, sw_);   // swz24
    apply_gate<5>(a2, cst, lane, sw_);   // local reg^24
    apply_gate<1>(a2, cst, lane, sw_);   // swz12
    apply_gate<3>(a2, cst, lane, sw_);   // DPP xor3
    apply_gate<2>(a2, cst, lane, sw_);   // swz6
    apply_gate<6>(a2, cst, lane, sw_);   // local reg^12
    apply_gate<9>(a2, cst, lane, sw_);   // swz24 (reg^1)
    apply_gate<4>(a2, cst, lane, sw_);   // DPP xor1 (reg^16)
    apply_gate<7>(a2, cst, lane, sw_);   // local reg^6
    apply_gate<8>(a2, cst, lane, sw_);   // local reg^3

    // ---- probabilities + reg-WHT stages 1,2,4,8 (stage 16 pruned into e[q])
    float wv[32];
    #pragma unroll
    for (int r = 0; r < 32; ++r) wv[r] = a2[r].x * a2[r].x + a2[r].y * a2[r].y;
    #pragma unroll
    for (int bS = 1; bS < 16; bS <<= 1) {
        #pragma unroll
        for (int r = 0; r < 32; ++r) {
            if (!(r & bS)) {
                float xv = wv[r], yv = wv[r | bS];
                wv[r]      = xv + yv;
                wv[r | bS] = xv - yv;
            }
        }
    }

    float e[10];
    #pragma unroll
    for (int q = 0; q < 10; ++q) {
        const int R = CC.sgnR[q];
        float num = (R & 16) ? (wv[R ^ 16] - wv[R]) : (wv[R] + wv[R ^ 16]);
        int slq = __popc(unsigned(l5 & CC.sgnL[q])) & 1;
        e[q] = csw(num, slq << 31);
    }

    // ---- lane reduction within each 32-half: DPP quad-reduce, slot-pack to
    //      3, swizzle xor4/8/16 (no xor32: halves are different samples)
    #pragma unroll
    for (int q = 0; q < 10; ++q) {
        e[q] += fetch<1>(e[q], lane);
        e[q] += fetch<2>(e[q], lane);
    }
    int s = l5 & 3;
    bool s1 = (s & 1) != 0, s2 = (s & 2) != 0;
    float v0 = s1 ? e[1] : e[0];
    float u0 = s1 ? e[3] : e[2];
    v0 = s2 ? u0 : v0;
    float v1 = s1 ? e[5] : e[4];
    float u1 = s1 ? e[7] : e[6];
    v1 = s2 ? u1 : v1;
    float v2 = s1 ? e[9] : e[8];

    v0 += fetch<4>(v0, lane);   v1 += fetch<4>(v1, lane);   v2 += fetch<4>(v2, lane);
    v0 += fetch<8>(v0, lane);   v1 += fetch<8>(v1, lane);   v2 += fetch<8>(v2, lane);
    v0 += fetch<16>(v0, lane);  v1 += fetch<16>(v1, lane);  v2 += fetch<16>(v2, lane);

    // lane l5==q holds full sum of e[q] in v_{q>>2} (slot matches l5&3)
    float vo = v0;
    int hi = l5 >> 2;
    vo = (hi == 1) ? v1 : vo;
    vo = (hi == 2) ? v2 : vo;
    if (l5 < 10) out[b * 10 + l5] = vo;
}

extern "C" void kernel_launch(void* const* d_in, const int* in_sizes, int n_in,
                              void* d_out, int out_size, void* d_ws, size_t ws_size,
                              hipStream_t stream) {
    const float* x  = (const float*)d_in[0];
    const float* qw = (const float*)d_in[1];
    float* out = (float*)d_out;
    int B = in_sizes[0] / 10;
    int blocks = (B + 7) / 8;   // 8 samples per 256-thread block (2 per wave)
    hipLaunchKernelGGL(qprep, dim3(1), dim3(64), 0, stream, qw);
    hipLaunchKernelGGL(qsim, dim3(blocks), dim3(256), 0, stream, x, out, B);
}